// Round 10
// baseline (116.627 us; speedup 1.0000x reference)
//
#include <hip/hip_runtime.h>

typedef __attribute__((ext_vector_type(8))) _Float16 half8;
typedef __attribute__((ext_vector_type(4))) _Float16 half4;
typedef __attribute__((ext_vector_type(2))) __fp16 fp16x2;
typedef __attribute__((ext_vector_type(4))) float f32x4;
typedef __attribute__((ext_vector_type(4))) unsigned int u32x4;
typedef __attribute__((ext_vector_type(2))) unsigned int u32x2;

#define NSEQ 2048
#define DIMM 1024
#define NH   16
#define HD   64

typedef const void __attribute__((address_space(1))) gvoid_t;
typedef void __attribute__((address_space(3))) svoid_t;

__device__ __forceinline__ void gload_lds16(const void* g, void* l) {
  __builtin_amdgcn_global_load_lds((gvoid_t*)g, (svoid_t*)l, 16, 0, 0);
}

union H2U { fp16x2 h; unsigned int u; };

// ---------------- fused fp32 -> fp16 convert (x, w_qkv, w_out in one launch) ----
__global__ __launch_bounds__(256) void cvt_all(const float* __restrict__ x,
                                               const float* __restrict__ wqkv,
                                               const float* __restrict__ wout,
                                               _Float16* __restrict__ xh,
                                               _Float16* __restrict__ wqkvh,
                                               _Float16* __restrict__ wouth) {
  int i = blockIdx.x * 256 + threadIdx.x;
  const float* src;
  _Float16* dst;
  int off;
  if (i < 524288) { src = x; dst = xh; off = i; }
  else if (i < 917504) { src = wqkv; dst = wqkvh; off = i - 524288; }
  else { src = wout; dst = wouth; off = i - 917504; }
  const float4* p = (const float4*)src + (size_t)off * 2;
  float4 v0 = p[0], v1 = p[1];
  half8 h;
  h[0] = (_Float16)v0.x; h[1] = (_Float16)v0.y; h[2] = (_Float16)v0.z; h[3] = (_Float16)v0.w;
  h[4] = (_Float16)v1.x; h[5] = (_Float16)v1.y; h[6] = (_Float16)v1.z; h[7] = (_Float16)v1.w;
  *((half8*)dst + off) = h;
}

// ---- NT GEMM mainloop: 128x128 C-tile of A[M,1024] * B[N,1024]^T, BK=32 ----
__device__ __forceinline__ void gemm_mainloop(const _Float16* __restrict__ A,
                                              const _Float16* __restrict__ B,
                                              int am0, int bn0,
                                              _Float16* As, _Float16* Bs,
                                              f32x4 acc[4][4]) {
  const int tid = threadIdx.x;
  const int w = tid >> 6, lane = tid & 63;
  const int lr = lane >> 2;
  const int lc = (lane & 3) * 8;
  const int wm = (w >> 1) * 64, wn = (w & 1) * 64;
  const int g = lane >> 4, ln = lane & 15;

  for (int k0 = 0; k0 < 1024; k0 += 32) {
#pragma unroll
    for (int rr = 0; rr < 4; ++rr) {
      int c = rr * 4 + w;
      if (c < 8) {
        gload_lds16(A + (size_t)(am0 + c * 16 + lr) * 1024 + k0 + lc, As + c * 512);
      } else {
        int cb = c - 8;
        gload_lds16(B + (size_t)(bn0 + cb * 16 + lr) * 1024 + k0 + lc, Bs + cb * 512);
      }
    }
    __syncthreads();
    half8 af[4], bf[4];
#pragma unroll
    for (int mi = 0; mi < 4; ++mi)
      af[mi] = *(const half8*)(As + (wm + mi * 16 + ln) * 32 + g * 8);
#pragma unroll
    for (int ni = 0; ni < 4; ++ni)
      bf[ni] = *(const half8*)(Bs + (wn + ni * 16 + ln) * 32 + g * 8);
#pragma unroll
    for (int mi = 0; mi < 4; ++mi)
#pragma unroll
      for (int ni = 0; ni < 4; ++ni)
        acc[mi][ni] = __builtin_amdgcn_mfma_f32_16x16x32_f16(af[mi], bf[ni], acc[mi][ni], 0, 0, 0);
    __syncthreads();
  }
}

// ---------------- kernel 1: qkv = x @ w_qkv^T, scatter epilogue ----------------
union SmemQKV {
  struct { _Float16 a[128 * 32]; _Float16 b[128 * 32]; } ab;
  _Float16 t[128 * 136];
};

// Q pre-scaled by SCALE * log2(e) so attention works in exp2 domain.
#define QSCALE 0.0450843450f

__global__ __launch_bounds__(256) void gemm_qkv(const _Float16* __restrict__ x,
                                                const _Float16* __restrict__ wqkv,
                                                _Float16* __restrict__ qh,
                                                _Float16* __restrict__ kh,
                                                _Float16* __restrict__ vt) {
  __shared__ SmemQKV sh;
  f32x4 acc[4][4];
#pragma unroll
  for (int i = 0; i < 4; ++i)
#pragma unroll
    for (int j = 0; j < 4; ++j) acc[i][j] = (f32x4){0.f, 0.f, 0.f, 0.f};
  const int bm = blockIdx.x, bn = blockIdx.y;
  gemm_mainloop(x, wqkv, bm * 128, bn * 128, sh.ab.a, sh.ab.b, acc);

  const int tid = threadIdx.x;
  const int w = tid >> 6, lane = tid & 63;
  const int g = lane >> 4, ln = lane & 15;
  const int wm = (w >> 1) * 64, wn = (w & 1) * 64;
  const int sec = bn >> 3;
  const int cbase = (bn & 7) * 128;

  if (sec < 2) {
    _Float16* dst = (sec == 0) ? qh : kh;
    const float scale = (sec == 0) ? QSCALE : 1.0f;
#pragma unroll
    for (int mi = 0; mi < 4; ++mi) {
      int row = bm * 128 + wm + mi * 16 + g * 4;
      int bidx = row >> 11, nidx = row & 2047;
#pragma unroll
      for (int ni = 0; ni < 4; ++ni) {
        int col = cbase + wn + ni * 16 + ln;
        int h = col >> 6, d = col & 63;
        _Float16* p = dst + ((size_t)(bidx * NH + h) * NSEQ + nidx) * HD + d;
#pragma unroll
        for (int r = 0; r < 4; ++r) p[r * HD] = (_Float16)(acc[mi][ni][r] * scale);
      }
    }
  } else {
    __syncthreads();
#pragma unroll
    for (int mi = 0; mi < 4; ++mi)
#pragma unroll
      for (int ni = 0; ni < 4; ++ni)
#pragma unroll
        for (int r = 0; r < 4; ++r)
          sh.t[(wn + ni * 16 + ln) * 136 + wm + mi * 16 + g * 4 + r] = (_Float16)acc[mi][ni][r];
    __syncthreads();
    const int row0 = bm * 128;
    const int bidx = row0 >> 11, n0 = row0 & 2047;
#pragma unroll
    for (int i = 0; i < 8; ++i) {
      int ci = i * 256 + tid;
      int drow = ci >> 4, nofs = (ci & 15) * 8;
      int col = cbase + drow;
      int h = col >> 6, d = col & 63;
      u32x4 val = *(const u32x4*)(sh.t + drow * 136 + nofs);
      *(u32x4*)(vt + ((size_t)(bidx * NH + h) * HD + d) * NSEQ + n0 + nofs) = val;
    }
  }
}

// ---------------- kernel 2: flash attention, T15 intra-wave pipeline ------------
// R4 geometry (32q x 64k per wave, P [32q][128B] slot^ln swizzle, 0 conflicts),
// R9 triple-buffer 1-barrier staging. NEW: 2-tile software pipeline inside each
// wave: QK(t+1) MFMAs are issued between the two softmax halves of tile t, so
// the exp2 VALU chain executes while the MFMA pipe computes S(t+1), and the PV
// P-roundtrip stall is covered by the draining QK MFMAs. sacc is double-state
// (named saccA/saccB, unroll-by-2 -- no dynamic indexing); LDS buffer indices
// are rotating scalar ints (cur,nxt,stg = permutation of 0,1,2).
__global__ __launch_bounds__(256, 2) void attn_fwd(const _Float16* __restrict__ qg,
                                                   const _Float16* __restrict__ kg,
                                                   const _Float16* __restrict__ vg,
                                                   _Float16* __restrict__ ao) {
  __shared__ _Float16 Ks[3][64 * 64];   // 24 KB
  __shared__ _Float16 Vs[3][64 * 64];   // 24 KB
  __shared__ _Float16 Ps[4][32 * 64];   // 16 KB: per-wave P, 128 B rows

  const int bid = blockIdx.x;
  const int swz = (bid & 7) * 64 + (bid >> 3);     // bijective: 512 % 8 == 0
  const int bh = swz >> 4, qt = swz & 15;
  const int tid = threadIdx.x, w = tid >> 6, lane = tid & 63;
  const int g = lane >> 4, ln = lane & 15;
  const int sw8 = ln & 7;

  const _Float16* qp = qg + (size_t)bh * NSEQ * HD;
  const _Float16* kp = kg + (size_t)bh * NSEQ * HD;
  const _Float16* vp = vg + (size_t)bh * HD * NSEQ;
  char* psw = (char*)&Ps[w][0];

  const int qr = qt * 128 + w * 32;

  // Q fragments (B-operand): qf[qb][dk] = Q[qr+qb*16+ln][dk*32+g*8 ..+8]
  half8 qf[2][2];
#pragma unroll
  for (int qb = 0; qb < 2; ++qb)
#pragma unroll
    for (int dk = 0; dk < 2; ++dk)
      qf[qb][dk] = *(const half8*)(qp + (size_t)(qr + qb * 16 + ln) * HD + dk * 32 + g * 8);
  asm volatile("" ::: "memory");   // pin Q loads before staging (vmcnt accounting)

  // staging: wave w loads chunks {2w,2w+1} of K and V; source pre-swizzled (G21)
  const int rsub = lane >> 3;
  const int csw = ((lane & 7) ^ rsub) << 3;
  const int c0 = 2 * w;

#define STAGE(buf, tt)                                                              \
  {                                                                                 \
    const _Float16* kt_ = kp + (size_t)(tt) * 64 * HD;                              \
    _Pragma("unroll")                                                               \
    for (int i = 0; i < 2; ++i) {                                                   \
      int c = c0 + i;                                                               \
      gload_lds16(kt_ + (size_t)(c * 8 + rsub) * HD + csw, &Ks[buf][c * 512]);      \
    }                                                                               \
    _Pragma("unroll")                                                               \
    for (int i = 0; i < 2; ++i) {                                                   \
      int c = c0 + i;                                                               \
      gload_lds16(vp + (size_t)(c * 8 + rsub) * NSEQ + (tt) * 64 + csw,             \
                  &Vs[buf][c * 512]);                                               \
    }                                                                               \
  }

  STAGE(0, 0);
  STAGE(1, 1);

  float lsum[2] = {0.f, 0.f};
  f32x4 oacc[4][2];    // [sd][qb]
#pragma unroll
  for (int sd = 0; sd < 4; ++sd)
#pragma unroll
    for (int qb = 0; qb < 2; ++qb) oacc[sd][qb] = (f32x4){0.f, 0.f, 0.f, 0.f};
  const f32x4 fz = (f32x4){0.f, 0.f, 0.f, 0.f};

  // --- phase macros -------------------------------------------------------------
  // QK: read kf from Ks[nb], 8 MFMAs into SN (S(t+1)).
#define QK_PHASE(SN, nb)                                                            \
  {                                                                                 \
    const _Float16* kb_ = &Ks[0][0] + (nb) * 4096;                                  \
    half8 kf0, kf1;                                                                 \
    _Pragma("unroll")                                                               \
    for (int s = 0; s < 4; ++s) {                                                   \
      const _Float16* kr = kb_ + (s * 16 + ln) * 64;                                \
      kf0 = *(const half8*)(kr + ((g ^ sw8) << 3));                                 \
      kf1 = *(const half8*)(kr + (((4 + g) ^ sw8) << 3));                           \
      SN[s][0] = __builtin_amdgcn_mfma_f32_16x16x32_f16(kf0, qf[0][0], fz, 0, 0, 0);        \
      SN[s][0] = __builtin_amdgcn_mfma_f32_16x16x32_f16(kf1, qf[0][1], SN[s][0], 0, 0, 0);  \
      SN[s][1] = __builtin_amdgcn_mfma_f32_16x16x32_f16(kf0, qf[1][0], fz, 0, 0, 0);        \
      SN[s][1] = __builtin_amdgcn_mfma_f32_16x16x32_f16(kf1, qf[1][1], SN[s][1], 0, 0, 0);  \
    }                                                                               \
  }

  // softmax half for one qb: 16 exp2 + pack + P-write + partial sum.
#define SM_HALF(SC, qb)                                                             \
  {                                                                                 \
    const int q = (qb) * 16 + ln;                                                   \
    float rs = 0.f;                                                                 \
    _Pragma("unroll")                                                               \
    for (int s = 0; s < 4; ++s) {                                                   \
      float e0 = __builtin_amdgcn_exp2f(SC[s][qb][0]);                              \
      float e1 = __builtin_amdgcn_exp2f(SC[s][qb][1]);                              \
      float e2 = __builtin_amdgcn_exp2f(SC[s][qb][2]);                              \
      float e3 = __builtin_amdgcn_exp2f(SC[s][qb][3]);                              \
      rs += (e0 + e1) + (e2 + e3);                                                  \
      H2U a_, b_;                                                                   \
      a_.h = __builtin_amdgcn_cvt_pkrtz(e0, e1);                                    \
      b_.h = __builtin_amdgcn_cvt_pkrtz(e2, e3);                                    \
      u32x2 quad; quad[0] = a_.u; quad[1] = b_.u;                                   \
      const int kq = s * 4 + g;                                                     \
      *(u32x2*)(psw + q * 128 + ((kq ^ ln) << 3)) = quad;                           \
    }                                                                               \
    lsum[qb] += rs;                                                                 \
  }

  // PV: vf already read into vf_[]; fence P, read pb, 8 MFMAs.
#define PV_PHASE(vf_)                                                               \
  {                                                                                 \
    asm volatile("s_waitcnt lgkmcnt(0)" ::: "memory");                              \
    half8 pb[2][2];                                                                 \
    _Pragma("unroll")                                                               \
    for (int qb = 0; qb < 2; ++qb) {                                                \
      const int q = qb * 16 + ln;                                                   \
      _Pragma("unroll")                                                             \
      for (int f = 0; f < 2; ++f) {                                                 \
        const int qd = (f * 4 + g) * 2;                                             \
        u32x2 lo = *(const u32x2*)(psw + q * 128 + ((qd ^ ln) << 3));               \
        u32x2 hi = *(const u32x2*)(psw + q * 128 + (((qd + 1) ^ ln) << 3));         \
        union { u32x4 u; half8 h; } pk;                                             \
        pk.u[0] = lo[0]; pk.u[1] = lo[1]; pk.u[2] = hi[0]; pk.u[3] = hi[1];         \
        pb[qb][f] = pk.h;                                                           \
      }                                                                             \
    }                                                                               \
    __builtin_amdgcn_s_setprio(1);                                                  \
    _Pragma("unroll")                                                               \
    for (int sd = 0; sd < 4; ++sd) {                                                \
      _Pragma("unroll")                                                             \
      for (int qb = 0; qb < 2; ++qb) {                                              \
        oacc[sd][qb] = __builtin_amdgcn_mfma_f32_16x16x32_f16(vf_[sd][0], pb[qb][0], oacc[sd][qb], 0, 0, 0); \
        oacc[sd][qb] = __builtin_amdgcn_mfma_f32_16x16x32_f16(vf_[sd][1], pb[qb][1], oacc[sd][qb], 0, 0, 0); \
      }                                                                             \
    }                                                                               \
    __builtin_amdgcn_s_setprio(0);                                                  \
  }

#define VF_READ(vf_, cb)                                                            \
  {                                                                                 \
    const _Float16* vb_ = &Vs[0][0] + (cb) * 4096;                                  \
    _Pragma("unroll")                                                               \
    for (int sd = 0; sd < 4; ++sd) {                                                \
      const _Float16* vr = vb_ + (sd * 16 + ln) * 64;                               \
      vf_[sd][0] = *(const half8*)(vr + ((g ^ sw8) << 3));                          \
      vf_[sd][1] = *(const half8*)(vr + (((4 + g) ^ sw8) << 3));                    \
    }                                                                               \
  }

  // body(t): SC = S(t) [computed], SN <- S(t+1). Stages tile t+2 if DO_STAGE.
#define BODY(SC, SN, tt, DO_STAGE)                                                  \
  {                                                                                 \
    asm volatile("s_waitcnt vmcnt(0)" ::: "memory");  /* STAGE(t+1) landed */       \
    __builtin_amdgcn_s_barrier();                     /* nobody reads stg buf */    \
    if (DO_STAGE) STAGE(stg, (tt) + 2);                                             \
    SM_HALF(SC, 0)                                                                  \
    QK_PHASE(SN, nxt)          /* MFMAs run under SM_HALF(1)'s VALU */              \
    half8 vf_[4][2];                                                                \
    VF_READ(vf_, cur)                                                               \
    SM_HALF(SC, 1)                                                                  \
    PV_PHASE(vf_)                                                                   \
    int tmp_ = cur; cur = nxt; nxt = stg; stg = tmp_;                               \
  }

  // prologue: tiles 0,1 staged; compute S(0)
  asm volatile("s_waitcnt vmcnt(4)" ::: "memory");   // own STAGE(0) landed
  __builtin_amdgcn_s_barrier();                      // everyone's STAGE(0) landed
  f32x4 saccA[4][2], saccB[4][2];
  int cur = 0, nxt = 1, stg = 2;
  QK_PHASE(saccA, 0)

  for (int t = 0; t < 30; t += 2) {
    BODY(saccA, saccB, t, 1)
    BODY(saccB, saccA, t + 1, 1)
  }
  BODY(saccA, saccB, 30, 0)   // t=30: QK(31), no stage
  {                           // t=31: softmax+PV only
    half8 vf_[4][2];
    VF_READ(vf_, cur)
    SM_HALF(saccB, 0)
    SM_HALF(saccB, 1)
    PV_PHASE(vf_)
  }

  // epilogue: cross-g lsum reduce, normalize, store (wave-private)
  const int bidx = bh >> 4, h = bh & 15;
#pragma unroll
  for (int qb = 0; qb < 2; ++qb) {
    lsum[qb] += __shfl_xor(lsum[qb], 16, 64);
    lsum[qb] += __shfl_xor(lsum[qb], 32, 64);
    const float inv = 1.f / lsum[qb];
    const int n = qr + qb * 16 + ln;
#pragma unroll
    for (int sd = 0; sd < 4; ++sd) {
      half4 o4;
#pragma unroll
      for (int r = 0; r < 4; ++r) o4[r] = (_Float16)(oacc[sd][qb][r] * inv);
      *(half4*)(ao + (size_t)(bidx * NSEQ + n) * DIMM + h * HD + sd * 16 + g * 4) = o4;
    }
  }
}

// ---------------- kernel 3: out = ao @ w_out^T + b_out (fp32 out) ----------------
__global__ __launch_bounds__(256) void gemm_out(const _Float16* __restrict__ ao,
                                                const _Float16* __restrict__ wout,
                                                const float* __restrict__ bias,
                                                float* __restrict__ out) {
  __shared__ _Float16 As[128 * 32];
  __shared__ _Float16 Bs[128 * 32];
  f32x4 acc[4][4];
#pragma unroll
  for (int i = 0; i < 4; ++i)
#pragma unroll
    for (int j = 0; j < 4; ++j) acc[i][j] = (f32x4){0.f, 0.f, 0.f, 0.f};
  const int bm = blockIdx.x, bn = blockIdx.y;
  gemm_mainloop(ao, wout, bm * 128, bn * 128, As, Bs, acc);
  const int tid = threadIdx.x;
  const int w = tid >> 6, lane = tid & 63;
  const int g = lane >> 4, ln = lane & 15;
  const int wm = (w >> 1) * 64, wn = (w & 1) * 64;
#pragma unroll
  for (int mi = 0; mi < 4; ++mi) {
    const int row = bm * 128 + wm + mi * 16 + g * 4;
#pragma unroll
    for (int ni = 0; ni < 4; ++ni) {
      const int col = bn * 128 + wn + ni * 16 + ln;
      const float b = bias[col];
#pragma unroll
      for (int r = 0; r < 4; ++r) out[(size_t)(row + r) * DIMM + col] = acc[mi][ni][r] + b;
    }
  }
}

extern "C" void kernel_launch(void* const* d_in, const int* in_sizes, int n_in,
                              void* d_out, int out_size, void* d_ws, size_t ws_size,
                              hipStream_t stream) {
  const float* x    = (const float*)d_in[0];
  const float* wqkv = (const float*)d_in[1];
  const float* wout = (const float*)d_in[2];
  const float* bout = (const float*)d_in[3];
  float* out = (float*)d_out;

  _Float16* ws = (_Float16*)d_ws;
  _Float16* x_h    = ws;
  _Float16* wqkv_h = ws + (4u << 20);
  _Float16* wout_h = ws + (7u << 20);
  _Float16* q_h    = ws + (8u << 20);   // [b,h,n,64], pre-scaled by 1/32*log2e
  _Float16* k_h    = ws + (12u << 20);  // [b,h,n,64]
  _Float16* vt_h   = ws + (16u << 20);  // [b,h,64,n]
  _Float16* ao_h   = ws + (20u << 20);  // [b*n, 1024]

  cvt_all<<<dim3(4096), 256, 0, stream>>>(x, wqkv, wout, x_h, wqkv_h, wout_h);
  gemm_qkv<<<dim3(32, 24), 256, 0, stream>>>(x_h, wqkv_h, q_h, k_h, vt_h);
  attn_fwd<<<dim3(512), 256, 0, stream>>>(q_h, k_h, vt_h, ao_h);
  gemm_out<<<dim3(32, 8), 256, 0, stream>>>(ao_h, wout_h, bout, out);
}

// Round 11
// 107.650 us; speedup vs baseline: 1.0834x; 1.0834x over previous
//
#include <hip/hip_runtime.h>

typedef __attribute__((ext_vector_type(8))) _Float16 half8;
typedef __attribute__((ext_vector_type(4))) _Float16 half4;
typedef __attribute__((ext_vector_type(2))) __fp16 fp16x2;
typedef __attribute__((ext_vector_type(4))) float f32x4;
typedef __attribute__((ext_vector_type(4))) unsigned int u32x4;
typedef __attribute__((ext_vector_type(2))) unsigned int u32x2;

#define NSEQ 2048
#define DIMM 1024
#define NH   16
#define HD   64

typedef const void __attribute__((address_space(1))) gvoid_t;
typedef void __attribute__((address_space(3))) svoid_t;

__device__ __forceinline__ void gload_lds16(const void* g, void* l) {
  __builtin_amdgcn_global_load_lds((gvoid_t*)g, (svoid_t*)l, 16, 0, 0);
}

union H2U { fp16x2 h; unsigned int u; };

// ---------------- fused fp32 -> fp16 convert (x, w_qkv, w_out in one launch) ----
__global__ __launch_bounds__(256) void cvt_all(const float* __restrict__ x,
                                               const float* __restrict__ wqkv,
                                               const float* __restrict__ wout,
                                               _Float16* __restrict__ xh,
                                               _Float16* __restrict__ wqkvh,
                                               _Float16* __restrict__ wouth) {
  int i = blockIdx.x * 256 + threadIdx.x;
  const float* src;
  _Float16* dst;
  int off;
  if (i < 524288) { src = x; dst = xh; off = i; }
  else if (i < 917504) { src = wqkv; dst = wqkvh; off = i - 524288; }
  else { src = wout; dst = wouth; off = i - 917504; }
  const float4* p = (const float4*)src + (size_t)off * 2;
  float4 v0 = p[0], v1 = p[1];
  half8 h;
  h[0] = (_Float16)v0.x; h[1] = (_Float16)v0.y; h[2] = (_Float16)v0.z; h[3] = (_Float16)v0.w;
  h[4] = (_Float16)v1.x; h[5] = (_Float16)v1.y; h[6] = (_Float16)v1.z; h[7] = (_Float16)v1.w;
  *((half8*)dst + off) = h;
}

// ---- NT GEMM mainloop: 128x128 C-tile of A[M,1024] * B[N,1024]^T, BK=32 ----
__device__ __forceinline__ void gemm_mainloop(const _Float16* __restrict__ A,
                                              const _Float16* __restrict__ B,
                                              int am0, int bn0,
                                              _Float16* As, _Float16* Bs,
                                              f32x4 acc[4][4]) {
  const int tid = threadIdx.x;
  const int w = tid >> 6, lane = tid & 63;
  const int lr = lane >> 2;
  const int lc = (lane & 3) * 8;
  const int wm = (w >> 1) * 64, wn = (w & 1) * 64;
  const int g = lane >> 4, ln = lane & 15;

  for (int k0 = 0; k0 < 1024; k0 += 32) {
#pragma unroll
    for (int rr = 0; rr < 4; ++rr) {
      int c = rr * 4 + w;
      if (c < 8) {
        gload_lds16(A + (size_t)(am0 + c * 16 + lr) * 1024 + k0 + lc, As + c * 512);
      } else {
        int cb = c - 8;
        gload_lds16(B + (size_t)(bn0 + cb * 16 + lr) * 1024 + k0 + lc, Bs + cb * 512);
      }
    }
    __syncthreads();
    half8 af[4], bf[4];
#pragma unroll
    for (int mi = 0; mi < 4; ++mi)
      af[mi] = *(const half8*)(As + (wm + mi * 16 + ln) * 32 + g * 8);
#pragma unroll
    for (int ni = 0; ni < 4; ++ni)
      bf[ni] = *(const half8*)(Bs + (wn + ni * 16 + ln) * 32 + g * 8);
#pragma unroll
    for (int mi = 0; mi < 4; ++mi)
#pragma unroll
      for (int ni = 0; ni < 4; ++ni)
        acc[mi][ni] = __builtin_amdgcn_mfma_f32_16x16x32_f16(af[mi], bf[ni], acc[mi][ni], 0, 0, 0);
    __syncthreads();
  }
}

// ---------------- kernel 1: qkv = x @ w_qkv^T, scatter epilogue ----------------
union SmemQKV {
  struct { _Float16 a[128 * 32]; _Float16 b[128 * 32]; } ab;
  _Float16 t[128 * 136];
};

// Q pre-scaled by SCALE * log2(e) so attention works in exp2 domain.
#define QSCALE 0.0450843450f

__global__ __launch_bounds__(256) void gemm_qkv(const _Float16* __restrict__ x,
                                                const _Float16* __restrict__ wqkv,
                                                _Float16* __restrict__ qh,
                                                _Float16* __restrict__ kh,
                                                _Float16* __restrict__ vt) {
  __shared__ SmemQKV sh;
  f32x4 acc[4][4];
#pragma unroll
  for (int i = 0; i < 4; ++i)
#pragma unroll
    for (int j = 0; j < 4; ++j) acc[i][j] = (f32x4){0.f, 0.f, 0.f, 0.f};
  const int bm = blockIdx.x, bn = blockIdx.y;
  gemm_mainloop(x, wqkv, bm * 128, bn * 128, sh.ab.a, sh.ab.b, acc);

  const int tid = threadIdx.x;
  const int w = tid >> 6, lane = tid & 63;
  const int g = lane >> 4, ln = lane & 15;
  const int wm = (w >> 1) * 64, wn = (w & 1) * 64;
  const int sec = bn >> 3;
  const int cbase = (bn & 7) * 128;

  if (sec < 2) {
    _Float16* dst = (sec == 0) ? qh : kh;
    const float scale = (sec == 0) ? QSCALE : 1.0f;
#pragma unroll
    for (int mi = 0; mi < 4; ++mi) {
      int row = bm * 128 + wm + mi * 16 + g * 4;
      int bidx = row >> 11, nidx = row & 2047;
#pragma unroll
      for (int ni = 0; ni < 4; ++ni) {
        int col = cbase + wn + ni * 16 + ln;
        int h = col >> 6, d = col & 63;
        _Float16* p = dst + ((size_t)(bidx * NH + h) * NSEQ + nidx) * HD + d;
#pragma unroll
        for (int r = 0; r < 4; ++r) p[r * HD] = (_Float16)(acc[mi][ni][r] * scale);
      }
    }
  } else {
    __syncthreads();
#pragma unroll
    for (int mi = 0; mi < 4; ++mi)
#pragma unroll
      for (int ni = 0; ni < 4; ++ni)
#pragma unroll
        for (int r = 0; r < 4; ++r)
          sh.t[(wn + ni * 16 + ln) * 136 + wm + mi * 16 + g * 4 + r] = (_Float16)acc[mi][ni][r];
    __syncthreads();
    const int row0 = bm * 128;
    const int bidx = row0 >> 11, n0 = row0 & 2047;
#pragma unroll
    for (int i = 0; i < 8; ++i) {
      int ci = i * 256 + tid;
      int drow = ci >> 4, nofs = (ci & 15) * 8;
      int col = cbase + drow;
      int h = col >> 6, d = col & 63;
      u32x4 val = *(const u32x4*)(sh.t + drow * 136 + nofs);
      *(u32x4*)(vt + ((size_t)(bidx * NH + h) * HD + d) * NSEQ + n0 + nofs) = val;
    }
  }
}

// ---------------- kernel 2: flash attention, in-lane P (K-row permuted) ---------
// KEY IDEA: global_load_lds takes a per-lane GLOBAL address, so K rows can be
// permuted at staging time for free. Storing global K row 32a+8g+4b+r at LDS
// row (2a+b)*16+g*4+r makes QK^T's D-layout (lane g holds k = s*16+g*4+r)
// coincide with PV's B-operand layout (lane g needs k = f*32+g*8+j):
//   pb[qb][0] = pack8(exp2(sacc[0]), exp2(sacc[1]))   // k = 8g..8g+7
//   pb[qb][1] = pack8(exp2(sacc[2]), exp2(sacc[3]))   // k = 32+8g..+7
// -> P never touches LDS. Per-wave-tile LDS traffic halves (32->16 KB); the
// P-write/fence/P-read serial segment vanishes. lsum: lane's 16 k-values are a
// partition; cross-g shfl 16/32 reduce unchanged. R9 3-buf 1-barrier staging.
__global__ __launch_bounds__(256, 2) void attn_fwd(const _Float16* __restrict__ qg,
                                                   const _Float16* __restrict__ kg,
                                                   const _Float16* __restrict__ vg,
                                                   _Float16* __restrict__ ao) {
  __shared__ _Float16 Ks[3][64 * 64];   // 24 KB
  __shared__ _Float16 Vs[3][64 * 64];   // 24 KB

  const int bid = blockIdx.x;
  const int swz = (bid & 7) * 64 + (bid >> 3);     // bijective: 512 % 8 == 0
  const int bh = swz >> 4, qt = swz & 15;
  const int tid = threadIdx.x, w = tid >> 6, lane = tid & 63;
  const int g = lane >> 4, ln = lane & 15;
  const int sw8 = ln & 7;

  const _Float16* qp = qg + (size_t)bh * NSEQ * HD;
  const _Float16* kp = kg + (size_t)bh * NSEQ * HD;
  const _Float16* vp = vg + (size_t)bh * HD * NSEQ;

  const int qr = qt * 128 + w * 32;

  // Q fragments (B-operand): qf[qb][dk] = Q[qr+qb*16+ln][dk*32+g*8 ..+8]
  half8 qf[2][2];
#pragma unroll
  for (int qb = 0; qb < 2; ++qb)
#pragma unroll
    for (int dk = 0; dk < 2; ++dk)
      qf[qb][dk] = *(const half8*)(qp + (size_t)(qr + qb * 16 + ln) * HD + dk * 32 + g * 8);
  asm volatile("" ::: "memory");   // pin Q loads before staging (vmcnt accounting)

  // staging: wave w loads chunks {2w,2w+1}; K source rows permuted so that LDS
  // row R holds global row ksrc(R) = 32*(R>>5) + 8*((R>>2)&3) + 4*((R>>4)&1) + (R&3)
  const int rsub = lane >> 3;
  const int csw = ((lane & 7) ^ rsub) << 3;      // within-row bank swizzle (key R&7)
  const int c0 = 2 * w;
  const int R0 = c0 * 8 + rsub, R1 = R0 + 8;
  const int ks0 = 32 * (R0 >> 5) + 8 * ((R0 >> 2) & 3) + 4 * ((R0 >> 4) & 1) + (R0 & 3);
  const int ks1 = 32 * (R1 >> 5) + 8 * ((R1 >> 2) & 3) + 4 * ((R1 >> 4) & 1) + (R1 & 3);

#define STAGE(buf, tt)                                                              \
  {                                                                                 \
    const _Float16* kt_ = kp + (size_t)(tt) * 64 * HD;                              \
    gload_lds16(kt_ + (size_t)ks0 * HD + csw, &Ks[buf][c0 * 512]);                  \
    gload_lds16(kt_ + (size_t)ks1 * HD + csw, &Ks[buf][(c0 + 1) * 512]);            \
    gload_lds16(vp + (size_t)(c0 * 8 + rsub) * NSEQ + (tt) * 64 + csw,              \
                &Vs[buf][c0 * 512]);                                                \
    gload_lds16(vp + (size_t)((c0 + 1) * 8 + rsub) * NSEQ + (tt) * 64 + csw,        \
                &Vs[buf][(c0 + 1) * 512]);                                          \
  }

  STAGE(0, 0);
  STAGE(1, 1);

  float lsum[2] = {0.f, 0.f};
  f32x4 oacc[4][2];    // [sd][qb]
#pragma unroll
  for (int sd = 0; sd < 4; ++sd)
#pragma unroll
    for (int qb = 0; qb < 2; ++qb) oacc[sd][qb] = (f32x4){0.f, 0.f, 0.f, 0.f};
  const f32x4 fz = (f32x4){0.f, 0.f, 0.f, 0.f};

#define TILE_BODY(kbuf, vbuf)                                                       \
  {                                                                                 \
    const _Float16* kb_ = (kbuf);                                                   \
    const _Float16* vb_ = (vbuf);                                                   \
    f32x4 sacc[4][2];                                                               \
    __builtin_amdgcn_s_setprio(1);                                                  \
    _Pragma("unroll")                                                               \
    for (int s = 0; s < 4; ++s) {                                                   \
      const _Float16* kr = kb_ + (s * 16 + ln) * 64;                                \
      half8 kf0 = *(const half8*)(kr + ((g ^ sw8) << 3));                           \
      half8 kf1 = *(const half8*)(kr + (((4 + g) ^ sw8) << 3));                     \
      sacc[s][0] = __builtin_amdgcn_mfma_f32_16x16x32_f16(kf0, qf[0][0], fz, 0, 0, 0);            \
      sacc[s][0] = __builtin_amdgcn_mfma_f32_16x16x32_f16(kf1, qf[0][1], sacc[s][0], 0, 0, 0);    \
      sacc[s][1] = __builtin_amdgcn_mfma_f32_16x16x32_f16(kf0, qf[1][0], fz, 0, 0, 0);            \
      sacc[s][1] = __builtin_amdgcn_mfma_f32_16x16x32_f16(kf1, qf[1][1], sacc[s][1], 0, 0, 0);    \
    }                                                                               \
    __builtin_amdgcn_s_setprio(0);                                                  \
    half8 vf[4][2];                                                                 \
    _Pragma("unroll")                                                               \
    for (int sd = 0; sd < 4; ++sd) {                                                \
      const _Float16* vr = vb_ + (sd * 16 + ln) * 64;                               \
      vf[sd][0] = *(const half8*)(vr + ((g ^ sw8) << 3));                           \
      vf[sd][1] = *(const half8*)(vr + (((4 + g) ^ sw8) << 3));                     \
    }                                                                               \
    half8 pb[2][2];                                                                 \
    _Pragma("unroll")                                                               \
    for (int qb = 0; qb < 2; ++qb) {                                                \
      float e[4][4];                                                                \
      float rs = 0.f;                                                               \
      _Pragma("unroll")                                                             \
      for (int s = 0; s < 4; ++s) {                                                 \
        e[s][0] = __builtin_amdgcn_exp2f(sacc[s][qb][0]);                           \
        e[s][1] = __builtin_amdgcn_exp2f(sacc[s][qb][1]);                           \
        e[s][2] = __builtin_amdgcn_exp2f(sacc[s][qb][2]);                           \
        e[s][3] = __builtin_amdgcn_exp2f(sacc[s][qb][3]);                           \
        rs += (e[s][0] + e[s][1]) + (e[s][2] + e[s][3]);                            \
      }                                                                             \
      lsum[qb] += rs;                                                               \
      H2U c00, c01, c10, c11, c20, c21, c30, c31;                                   \
      c00.h = __builtin_amdgcn_cvt_pkrtz(e[0][0], e[0][1]);                         \
      c01.h = __builtin_amdgcn_cvt_pkrtz(e[0][2], e[0][3]);                         \
      c10.h = __builtin_amdgcn_cvt_pkrtz(e[1][0], e[1][1]);                         \
      c11.h = __builtin_amdgcn_cvt_pkrtz(e[1][2], e[1][3]);                         \
      c20.h = __builtin_amdgcn_cvt_pkrtz(e[2][0], e[2][1]);                         \
      c21.h = __builtin_amdgcn_cvt_pkrtz(e[2][2], e[2][3]);                         \
      c30.h = __builtin_amdgcn_cvt_pkrtz(e[3][0], e[3][1]);                         \
      c31.h = __builtin_amdgcn_cvt_pkrtz(e[3][2], e[3][3]);                         \
      union { u32x4 u; half8 h; } p0, p1;                                           \
      p0.u[0] = c00.u; p0.u[1] = c01.u; p0.u[2] = c10.u; p0.u[3] = c11.u;           \
      p1.u[0] = c20.u; p1.u[1] = c21.u; p1.u[2] = c30.u; p1.u[3] = c31.u;           \
      pb[qb][0] = p0.h;                                                             \
      pb[qb][1] = p1.h;                                                             \
    }                                                                               \
    __builtin_amdgcn_s_setprio(1);                                                  \
    _Pragma("unroll")                                                               \
    for (int sd = 0; sd < 4; ++sd) {                                                \
      _Pragma("unroll")                                                             \
      for (int qb = 0; qb < 2; ++qb) {                                              \
        oacc[sd][qb] = __builtin_amdgcn_mfma_f32_16x16x32_f16(vf[sd][0], pb[qb][0], oacc[sd][qb], 0, 0, 0); \
        oacc[sd][qb] = __builtin_amdgcn_mfma_f32_16x16x32_f16(vf[sd][1], pb[qb][1], oacc[sd][qb], 0, 0, 0); \
      }                                                                             \
    }                                                                               \
    __builtin_amdgcn_s_setprio(0);                                                  \
  }

  for (int t = 0; t < 30; ++t) {
    asm volatile("s_waitcnt vmcnt(4)" ::: "memory");   // tile t resident; t+1 in flight
    __builtin_amdgcn_s_barrier();                      // all waves done with buf (t+2)%3
    STAGE((t + 2) % 3, t + 2);
    TILE_BODY(&Ks[t % 3][0], &Vs[t % 3][0])
  }
  {  // t = 30: no stage
    asm volatile("s_waitcnt vmcnt(4)" ::: "memory");
    __builtin_amdgcn_s_barrier();
    TILE_BODY(&Ks[0][0], &Vs[0][0])
  }
  {  // t = 31: full drain
    asm volatile("s_waitcnt vmcnt(0)" ::: "memory");
    __builtin_amdgcn_s_barrier();
    TILE_BODY(&Ks[1][0], &Vs[1][0])
  }

  // epilogue: cross-g lsum reduce, normalize, store (wave-private)
  const int bidx = bh >> 4, h = bh & 15;
#pragma unroll
  for (int qb = 0; qb < 2; ++qb) {
    lsum[qb] += __shfl_xor(lsum[qb], 16, 64);
    lsum[qb] += __shfl_xor(lsum[qb], 32, 64);
    const float inv = 1.f / lsum[qb];
    const int n = qr + qb * 16 + ln;
#pragma unroll
    for (int sd = 0; sd < 4; ++sd) {
      half4 o4;
#pragma unroll
      for (int r = 0; r < 4; ++r) o4[r] = (_Float16)(oacc[sd][qb][r] * inv);
      *(half4*)(ao + (size_t)(bidx * NSEQ + n) * DIMM + h * HD + sd * 16 + g * 4) = o4;
    }
  }
}

// ---------------- kernel 3: out = ao @ w_out^T + b_out (fp32 out) ----------------
__global__ __launch_bounds__(256) void gemm_out(const _Float16* __restrict__ ao,
                                                const _Float16* __restrict__ wout,
                                                const float* __restrict__ bias,
                                                float* __restrict__ out) {
  __shared__ _Float16 As[128 * 32];
  __shared__ _Float16 Bs[128 * 32];
  f32x4 acc[4][4];
#pragma unroll
  for (int i = 0; i < 4; ++i)
#pragma unroll
    for (int j = 0; j < 4; ++j) acc[i][j] = (f32x4){0.f, 0.f, 0.f, 0.f};
  const int bm = blockIdx.x, bn = blockIdx.y;
  gemm_mainloop(ao, wout, bm * 128, bn * 128, As, Bs, acc);
  const int tid = threadIdx.x;
  const int w = tid >> 6, lane = tid & 63;
  const int g = lane >> 4, ln = lane & 15;
  const int wm = (w >> 1) * 64, wn = (w & 1) * 64;
#pragma unroll
  for (int mi = 0; mi < 4; ++mi) {
    const int row = bm * 128 + wm + mi * 16 + g * 4;
#pragma unroll
    for (int ni = 0; ni < 4; ++ni) {
      const int col = bn * 128 + wn + ni * 16 + ln;
      const float b = bias[col];
#pragma unroll
      for (int r = 0; r < 4; ++r) out[(size_t)(row + r) * DIMM + col] = acc[mi][ni][r] + b;
    }
  }
}

extern "C" void kernel_launch(void* const* d_in, const int* in_sizes, int n_in,
                              void* d_out, int out_size, void* d_ws, size_t ws_size,
                              hipStream_t stream) {
  const float* x    = (const float*)d_in[0];
  const float* wqkv = (const float*)d_in[1];
  const float* wout = (const float*)d_in[2];
  const float* bout = (const float*)d_in[3];
  float* out = (float*)d_out;

  _Float16* ws = (_Float16*)d_ws;
  _Float16* x_h    = ws;
  _Float16* wqkv_h = ws + (4u << 20);
  _Float16* wout_h = ws + (7u << 20);
  _Float16* q_h    = ws + (8u << 20);   // [b,h,n,64], pre-scaled by 1/32*log2e
  _Float16* k_h    = ws + (12u << 20);  // [b,h,n,64]
  _Float16* vt_h   = ws + (16u << 20);  // [b,h,64,n]
  _Float16* ao_h   = ws + (20u << 20);  // [b*n, 1024]

  cvt_all<<<dim3(4096), 256, 0, stream>>>(x, wqkv, wout, x_h, wqkv_h, wout_h);
  gemm_qkv<<<dim3(32, 24), 256, 0, stream>>>(x_h, wqkv_h, q_h, k_h, vt_h);
  attn_fwd<<<dim3(512), 256, 0, stream>>>(q_h, k_h, vt_h, ao_h);
  gemm_out<<<dim3(32, 8), 256, 0, stream>>>(ao_h, wout_h, bout, out);
}